// Round 10
// baseline (184.448 us; speedup 1.0000x reference)
//
#include <hip/hip_runtime.h>
#include <hip/hip_bf16.h>
#include <math.h>

#define BATCH 8
#define SEQ   2048
#define EMB   1024
#define HEAD  64
#define BT    (BATCH * SEQ)

typedef __attribute__((ext_vector_type(8))) short  short8;
typedef __attribute__((ext_vector_type(4))) short  short4v;
typedef __attribute__((ext_vector_type(4))) float  floatx4;

__device__ __forceinline__ unsigned short f2bf(float x) {
    union { __hip_bfloat16 h; unsigned short u; } cv;
    cv.h = __float2bfloat16(x);   // RNE
    return cv.u;
}

// Barrier that does NOT drain vmcnt (LDS ordering only).
__device__ __forceinline__ void block_sync_lds() {
    asm volatile("s_waitcnt lgkmcnt(0)" ::: "memory");
    __builtin_amdgcn_s_barrier();
}

// =====================================================================
// Kernel 0: transpose+convert weights -> WT[192][1024] bf16.
// =====================================================================
__global__ __launch_bounds__(256) void wt_prep(
    const float* __restrict__ Wq, const float* __restrict__ Wk,
    const float* __restrict__ Wv, unsigned short* __restrict__ WT)
{
    __shared__ float tile[64][65];
    const int w  = blockIdx.x >> 4;        // 0..2
    const int k0 = (blockIdx.x & 15) * 64;
    const float* W = (w == 0) ? Wq : (w == 1) ? Wk : Wv;
    const int tid = threadIdx.x;

    for (int idx = tid; idx < 4096; idx += 256) {
        const int kr = idx >> 6, n = idx & 63;       // coalesced over n
        tile[kr][n] = W[(size_t)(k0 + kr) * HEAD + n];
    }
    __syncthreads();
    const int n  = tid >> 2;
    const int k8 = (tid & 3) * 16;
    unsigned short* dst = WT + (size_t)(w * 64 + n) * EMB + k0 + k8;
    short8 v0, v1;
#pragma unroll
    for (int j = 0; j < 8; ++j) v0[j] = (short)f2bf(tile[k8 + j][n]);
#pragma unroll
    for (int j = 0; j < 8; ++j) v1[j] = (short)f2bf(tile[k8 + 8 + j][n]);
    *(short8*)(dst)     = v0;
    *(short8*)(dst + 8) = v1;
}

// =====================================================================
// Kernel 1: QKV projection, SINGLE-STAGE LDS GEMM (no in-loop barriers).
// grid = BT/32 = 512 blocks x 512 thr (8 waves = 2M x 4N).
// Stage the full 32x1024 X tile once: 16 float4 loads/thread issued
// up-front (deep vmcnt pipeline), cvt bf16, swizzled ds_write
// (byte ^= (row&7)<<4 within 2048B rows), ONE lgkm barrier. Then
// 16 chunks x {2 ds_read_b128, 6 MFMA} with 2-deep W reg prefetch,
// zero barriers -- waves drift, TLP hides W L2 latency.
// Outputs: Q,K natural [t][64] bf16; V transposed VT[b][64][2048] bf16.
// =====================================================================
__global__ __launch_bounds__(512) void qkv_mfma(
    const float* __restrict__ X, const unsigned short* __restrict__ WT,
    unsigned short* __restrict__ Q, unsigned short* __restrict__ K,
    unsigned short* __restrict__ VT)
{
    __shared__ unsigned short Xs[32 * 1024];   // 64 KB bf16, swizzled

    const int tid = threadIdx.x;
    const int l   = tid & 63;
    const int wv  = tid >> 6;              // 0..7
    const int wm  = wv >> 2, wn = wv & 3;  // 2M x 4N
    const int g   = l >> 4,  q  = l & 15;
    const int row0 = blockIdx.x * 32;

    // ---- stage: thread owns row sr, cols sj*4 + i*64 (i=0..15) ----
    const int sr = tid >> 4, sj = tid & 15;
    const float* xsrc = X + (size_t)(row0 + sr) * EMB + sj * 4;
    char* const sbase = (char*)Xs + sr * 2048;
    const int ssw = (sr & 7) << 4;

    float4 xr[16];
#pragma unroll
    for (int i = 0; i < 16; ++i) xr[i] = *(const float4*)(xsrc + i * 64);

    // W(0) prefetch (survives the lgkm-only barrier)
    const unsigned short* wbase = WT + (size_t)(wn * 48 + q) * EMB + g * 8;
    short8 wreg[2][6];
#pragma unroll
    for (int nt = 0; nt < 3; ++nt)
#pragma unroll
        for (int kc = 0; kc < 2; ++kc)
            wreg[0][nt * 2 + kc] = *(const short8*)(wbase + (size_t)nt * 16 * EMB + kc * 32);

#pragma unroll
    for (int i = 0; i < 16; ++i) {
        short4v bb;
        bb[0] = (short)f2bf(xr[i].x); bb[1] = (short)f2bf(xr[i].y);
        bb[2] = (short)f2bf(xr[i].z); bb[3] = (short)f2bf(xr[i].w);
        *(short4v*)(sbase + ((sj * 8 + i * 128) ^ ssw)) = bb;
    }
    block_sync_lds();   // all ds_writes visible; W loads stay in flight

    // ---- compute: 16 chunks, no barriers ----
    const int rr  = wm * 16 + q;
    const int rsw = (rr & 7) << 4;
    const char* const rbase = (const char*)Xs + rr * 2048;

    floatx4 acc[3];
#pragma unroll
    for (int nt = 0; nt < 3; ++nt) acc[nt] = (floatx4){0.f, 0.f, 0.f, 0.f};

#pragma unroll
    for (int t = 0; t < 16; ++t) {
        if (t + 1 < 16) {
#pragma unroll
            for (int nt = 0; nt < 3; ++nt)
#pragma unroll
                for (int kc = 0; kc < 2; ++kc)
                    wreg[(t + 1) & 1][nt * 2 + kc] =
                        *(const short8*)(wbase + (size_t)nt * 16 * EMB + (t + 1) * 64 + kc * 32);
        }
#pragma unroll
        for (int kc = 0; kc < 2; ++kc) {
            const short8 a = *(const short8*)(rbase + ((t * 128 + kc * 64 + g * 16) ^ rsw));
#pragma unroll
            for (int nt = 0; nt < 3; ++nt)
                acc[nt] = __builtin_amdgcn_mfma_f32_16x16x32_bf16(
                    a, wreg[t & 1][nt * 2 + kc], acc[nt], 0, 0, 0);
        }
    }

    // C/D layout: col = lane&15 (=q), row = (lane>>4)*4 + r.
    const int trow0 = row0 + wm * 16 + g * 4;
#pragma unroll
    for (int nt = 0; nt < 3; ++nt) {
        const int c = wn * 48 + nt * 16 + q;
#pragma unroll
        for (int r = 0; r < 4; ++r) {
            const unsigned short v = f2bf(acc[nt][r]);
            const int t = trow0 + r;
            if (c < 64) {
                Q[(size_t)t * HEAD + c] = v;
            } else if (c < 128) {
                K[(size_t)t * HEAD + (c - 64)] = v;
            } else {
                const int bb = t >> 11, tl = t & (SEQ - 1);
                VT[((size_t)bb * HEAD + (c - 128)) * SEQ + tl] = v;
            }
        }
    }
}

// =====================================================================
// Kernel 2: causal flash attention, NO K/V LDS staging, no in-loop
// barriers. K/V per batch = 512 KB, reused by 64 blocks -> L2-resident;
// each wave reads its MFMA fragments directly from global.
// grid = 512 blocks x 256 thr (4 waves). Pair-split: waves {0,1} own
// even KV tiles, {2,3} odd; states merged via LDS at the end.
// Per owned tile: S MFMAs (kf regs) -> issue V loads -> issue K loads
// for tile kt+2 (same regs, ~600cy lead) -> softmax -> Ps (wave-local,
// lgkm fence) -> PV MFMAs.
// =====================================================================
__global__ __launch_bounds__(256) void attn_mfma(
    const unsigned short* __restrict__ Q, const unsigned short* __restrict__ K,
    const unsigned short* __restrict__ VT, float* __restrict__ O)
{
    __shared__ unsigned short Ps[64][72];      // [wv*16+q][kk]
    __shared__ float Mo[2][16][68];            // merge: pair-1 O partial
    __shared__ float Mm[2][16], Ml[2][16];     // merge: pair-1 m,l

    const int tid  = threadIdx.x;
    const int l    = tid & 63;
    const int wv   = tid >> 6;               // 0..3
    const int pair = wv >> 1, sub = wv & 1;
    const int g    = l >> 4, q = l & 15;
    const int qt   = 63 - (blockIdx.x >> 3); // largest-work blocks first
    const int b    = blockIdx.x & 7;
    const int qrow0 = qt * 32 + sub * 16;
    const size_t kbase = (size_t)b * SEQ * HEAD;
    const size_t vbase = (size_t)b * HEAD * SEQ;

    short8 bq[2];
#pragma unroll
    for (int dc = 0; dc < 2; ++dc)
        bq[dc] = *(const short8*)&Q[kbase + (size_t)(qrow0 + q) * HEAD + dc * 32 + g * 8];

    floatx4 o[4];
#pragma unroll
    for (int dt = 0; dt < 4; ++dt) o[dt] = (floatx4){0.f, 0.f, 0.f, 0.f};
    float m_run = -INFINITY, l_run = 0.f;

    const int nkt = (qt >> 1) + 1;

    // preload K frags for first owned tile (kt = pair; always in-bounds)
    short8 kf[4][2];
#pragma unroll
    for (int t = 0; t < 4; ++t)
#pragma unroll
        for (int dc = 0; dc < 2; ++dc)
            kf[t][dc] = *(const short8*)&K[kbase
                + (size_t)(pair * 64 + t * 16 + q) * HEAD + dc * 32 + g * 8];

    for (int kt = pair; kt < nkt; kt += 2) {
        // ---- S^T MFMAs (registers only) ----
        floatx4 s[4];
#pragma unroll
        for (int t = 0; t < 4; ++t) {
            s[t] = (floatx4){0.f, 0.f, 0.f, 0.f};
#pragma unroll
            for (int dc = 0; dc < 2; ++dc)
                s[t] = __builtin_amdgcn_mfma_f32_16x16x32_bf16(kf[t][dc], bq[dc], s[t], 0, 0, 0);
        }

        // ---- issue V loads for this tile (used after softmax) ----
        short8 vf[2][4];
#pragma unroll
        for (int kc = 0; kc < 2; ++kc)
#pragma unroll
            for (int dt = 0; dt < 4; ++dt)
                vf[kc][dt] = *(const short8*)&VT[vbase
                    + (size_t)(dt * 16 + q) * SEQ + kt * 64 + kc * 32 + g * 8];

        // ---- issue K loads for next owned tile (reuse kf regs) ----
        {
            const int ktn = (kt + 2 < nkt) ? (kt + 2) : 0;   // clamp: dummy, safe
#pragma unroll
            for (int t = 0; t < 4; ++t)
#pragma unroll
                for (int dc = 0; dc < 2; ++dc)
                    kf[t][dc] = *(const short8*)&K[kbase
                        + (size_t)(ktn * 64 + t * 16 + q) * HEAD + dc * 32 + g * 8];
        }

        // ---- scale + causal mask (diag tile only) ----
        float sv[4][4];
        if (kt == nkt - 1) {
#pragma unroll
            for (int t = 0; t < 4; ++t)
#pragma unroll
                for (int r = 0; r < 4; ++r) {
                    const int kg = kt * 64 + t * 16 + g * 4 + r;
                    sv[t][r] = (kg > qrow0 + q) ? -INFINITY : s[t][r] * 0.125f;
                }
        } else {
#pragma unroll
            for (int t = 0; t < 4; ++t)
#pragma unroll
                for (int r = 0; r < 4; ++r) sv[t][r] = s[t][r] * 0.125f;
        }

        // ---- online softmax (row = q, spread over 4 g-lanes) ----
        float pm = -INFINITY;
#pragma unroll
        for (int t = 0; t < 4; ++t)
#pragma unroll
            for (int r = 0; r < 4; ++r) pm = fmaxf(pm, sv[t][r]);
        pm = fmaxf(pm, __shfl_xor(pm, 16));
        pm = fmaxf(pm, __shfl_xor(pm, 32));
        const float mnew = fmaxf(m_run, pm);
        const float crow = __expf(m_run - mnew);   // first tile: exp(-inf)=0
        float p[4][4];
        float psum = 0.f;
#pragma unroll
        for (int t = 0; t < 4; ++t)
#pragma unroll
            for (int r = 0; r < 4; ++r) {
                p[t][r] = __expf(sv[t][r] - mnew);
                psum += p[t][r];
            }
        psum += __shfl_xor(psum, 16);
        psum += __shfl_xor(psum, 32);
        l_run = l_run * crow + psum;
        m_run = mnew;

#pragma unroll
        for (int r = 0; r < 4; ++r) {
            const float cr = __shfl(crow, g * 4 + r);
#pragma unroll
            for (int dt = 0; dt < 4; ++dt) o[dt][r] *= cr;
        }

        // ---- P -> LDS (wave-local region, lgkm fence only) ----
#pragma unroll
        for (int t = 0; t < 4; ++t) {
            const unsigned int lo = (unsigned)f2bf(p[t][0]) | ((unsigned)f2bf(p[t][1]) << 16);
            const unsigned int hi = (unsigned)f2bf(p[t][2]) | ((unsigned)f2bf(p[t][3]) << 16);
            *(unsigned int*)&Ps[wv * 16 + q][t * 16 + g * 4]     = lo;
            *(unsigned int*)&Ps[wv * 16 + q][t * 16 + g * 4 + 2] = hi;
        }
        asm volatile("s_waitcnt lgkmcnt(0)" ::: "memory");
        __builtin_amdgcn_sched_barrier(0);

        // ---- PV: O[q][d] += P[q][kk] * V[kk][d] ----
#pragma unroll
        for (int kc = 0; kc < 2; ++kc) {
            const short8 pa = *(const short8*)&Ps[wv * 16 + q][kc * 32 + g * 8];
#pragma unroll
            for (int dt = 0; dt < 4; ++dt)
                o[dt] = __builtin_amdgcn_mfma_f32_16x16x32_bf16(pa, vf[kc][dt], o[dt], 0, 0, 0);
        }
    }

    // ---- merge pair-1 state into pair-0, normalize, store fp32 ----
    __syncthreads();
    if (pair == 1) {
#pragma unroll
        for (int dt = 0; dt < 4; ++dt)
#pragma unroll
            for (int r = 0; r < 4; ++r)
                Mo[sub][g * 4 + r][dt * 16 + q] = o[dt][r];
        if (g == 0) { Mm[sub][q] = m_run; Ml[sub][q] = l_run; }
    }
    __syncthreads();
    if (pair == 0) {
        const float m1  = Mm[sub][q];
        const float l1v = Ml[sub][q];
        const float mx  = fmaxf(m_run, m1);
        const float c0  = __expf(m_run - mx);
        const float c1  = __expf(m1 - mx);     // m1=-inf (no odd tiles) -> 0
        const float lm  = l_run * c0 + l1v * c1;
        const size_t obase = (size_t)b * SEQ * HEAD;
#pragma unroll
        for (int r = 0; r < 4; ++r) {
            const float c0r = __shfl(c0, g * 4 + r);
            const float c1r = __shfl(c1, g * 4 + r);
            const float lr  = __shfl(lm, g * 4 + r);
            const float inv = 1.0f / lr;
#pragma unroll
            for (int dt = 0; dt < 4; ++dt) {
                const float val = o[dt][r] * c0r + Mo[sub][g * 4 + r][dt * 16 + q] * c1r;
                O[obase + (size_t)(qrow0 + g * 4 + r) * HEAD + dt * 16 + q] = val * inv;
            }
        }
    }
}

// =====================================================================
extern "C" void kernel_launch(void* const* d_in, const int* in_sizes, int n_in,
                              void* d_out, int out_size, void* d_ws, size_t ws_size,
                              hipStream_t stream)
{
    const float* X  = (const float*)d_in[0];
    const float* Wq = (const float*)d_in[1];
    const float* Wk = (const float*)d_in[2];
    const float* Wv = (const float*)d_in[3];
    float* O = (float*)d_out;

    unsigned short* Qb = (unsigned short*)d_ws;              // [BT][64] bf16
    unsigned short* Kb = Qb + (size_t)BT * HEAD;             // [BT][64]
    unsigned short* Vt = Kb + (size_t)BT * HEAD;             // [B][64][2048]
    unsigned short* WT = Vt + (size_t)BT * HEAD;             // [192][1024]

    wt_prep  <<<dim3(48),  dim3(256), 0, stream>>>(Wq, Wk, Wv, WT);
    qkv_mfma <<<dim3(512), dim3(512), 0, stream>>>(X, WT, Qb, Kb, Vt);
    attn_mfma<<<dim3(512), dim3(256), 0, stream>>>(Qb, Kb, Vt, O);
}